// Round 1
// baseline (882.161 us; speedup 1.0000x reference)
//
#include <hip/hip_runtime.h>
#include <hip/hip_bf16.h>

#define Bn 4
#define Sn 2048
#define Hn 8
#define Dn 64
#define En 512

typedef __attribute__((ext_vector_type(8))) short short8v;
typedef __attribute__((ext_vector_type(4))) float float4v;
typedef __attribute__((ext_vector_type(2))) unsigned int uint2v;

__device__ __forceinline__ short f2bf(float x){
    __hip_bfloat16 h = __float2bfloat16(x);
    return *reinterpret_cast<short*>(&h);
}
__device__ __forceinline__ float bf2f(short s){
    union { unsigned int u; float f; } c;
    c.u = ((unsigned int)(unsigned short)s) << 16;
    return c.f;
}
__device__ __forceinline__ unsigned int pack2(float lo, float hi){
    return (unsigned int)(unsigned short)f2bf(lo) | ((unsigned int)(unsigned short)f2bf(hi) << 16);
}

// ---------------- Wo fp32 -> bf16 ----------------
__global__ __launch_bounds__(256) void wo_cvt_kernel(const float* __restrict__ Wo,
                                                     short* __restrict__ Wob){
    int i = (blockIdx.x * 256 + threadIdx.x) * 4;
    float4 v = *(const float4*)(Wo + i);
    short4 o;
    o.x = f2bf(v.x); o.y = f2bf(v.y); o.z = f2bf(v.z); o.w = f2bf(v.w);
    *(short4*)(Wob + i) = o;
}

// ---------------- per-head input projections ----------------
// blockIdx.z: 0: values*Wv -> Vt[bh][d][k] (transposed); 1: keys*Wk -> Kp[bh][k][d]; 2: query*Wq -> Qp[bh][q][d]
__global__ __launch_bounds__(256) void proj_kernel(
    const float* __restrict__ values, const float* __restrict__ keys, const float* __restrict__ query,
    const float* __restrict__ Wv, const float* __restrict__ Wk, const float* __restrict__ Wq,
    short* __restrict__ Qp, short* __restrict__ Kp, short* __restrict__ Vt)
{
    const int sel = blockIdx.z;
    const float* X = (sel == 0) ? values : ((sel == 1) ? keys : query);
    const float* W = (sel == 0) ? Wv : ((sel == 1) ? Wk : Wq);
    const int bh = blockIdx.y;
    const int b = bh >> 3, h = bh & 7;
    const int s0 = blockIdx.x * 64;
    const int wave = threadIdx.x >> 6;
    const int lane = threadIdx.x & 63;
    const int l16 = lane & 15, quad = lane >> 4;

    // W-fragments: lane holds e = t*16+l16, d = st*32+quad*8+j (W rows are contiguous in d)
    short8v bw[4][2];
    #pragma unroll
    for (int t = 0; t < 4; t++){
      #pragma unroll
      for (int st = 0; st < 2; st++){
        const float* wp = W + (t*16 + l16)*64 + st*32 + quad*8;
        float4 w0 = *(const float4*)(wp);
        float4 w1 = *(const float4*)(wp + 4);
        short8v f;
        f[0]=f2bf(w0.x); f[1]=f2bf(w0.y); f[2]=f2bf(w0.z); f[3]=f2bf(w0.w);
        f[4]=f2bf(w1.x); f[5]=f2bf(w1.y); f[6]=f2bf(w1.z); f[7]=f2bf(w1.w);
        bw[t][st] = f;
      }
    }

    const int row = s0 + wave*16 + l16;
    short8v fa[2];
    #pragma unroll
    for (int st = 0; st < 2; st++){
        const float* xp = X + ((size_t)b*Sn + row)*En + h*Dn + st*32 + quad*8;
        float4 x0 = *(const float4*)(xp);
        float4 x1 = *(const float4*)(xp + 4);
        short8v f;
        f[0]=f2bf(x0.x); f[1]=f2bf(x0.y); f[2]=f2bf(x0.z); f[3]=f2bf(x0.w);
        f[4]=f2bf(x1.x); f[5]=f2bf(x1.y); f[6]=f2bf(x1.z); f[7]=f2bf(x1.w);
        fa[st] = f;
    }

    if (sel == 0){
        // D[row = s : quad*4+r][col = e : l16]  -> Vt[bh][e][k]: short4 along k
        const int rbase = s0 + wave*16 + quad*4;
        #pragma unroll
        for (int t = 0; t < 4; t++){
            float4v a = {0.f,0.f,0.f,0.f};
            a = __builtin_amdgcn_mfma_f32_16x16x32_bf16(fa[0], bw[t][0], a, 0,0,0);
            a = __builtin_amdgcn_mfma_f32_16x16x32_bf16(fa[1], bw[t][1], a, 0,0,0);
            int e = t*16 + l16;
            short4 pk;
            pk.x = f2bf(a[0]); pk.y = f2bf(a[1]); pk.z = f2bf(a[2]); pk.w = f2bf(a[3]);
            *(short4*)(Vt + ((size_t)bh*Dn + e)*Sn + rbase) = pk;   // 4 consecutive k
        }
    } else {
        // swapped: D[row = e : quad*4+r][col = s : l16] -> [s][d]: short4 along d (was 16x 2B scalar)
        short* dst = (sel == 1) ? Kp : Qp;
        #pragma unroll
        for (int t = 0; t < 4; t++){
            float4v a = {0.f,0.f,0.f,0.f};
            a = __builtin_amdgcn_mfma_f32_16x16x32_bf16(bw[t][0], fa[0], a, 0,0,0);
            a = __builtin_amdgcn_mfma_f32_16x16x32_bf16(bw[t][1], fa[1], a, 0,0,0);
            short4 pk;
            pk.x = f2bf(a[0]); pk.y = f2bf(a[1]); pk.z = f2bf(a[2]); pk.w = f2bf(a[3]);
            *(short4*)(dst + ((size_t)bh*Sn + row)*Dn + t*16 + quad*4) = pk;
        }
    }
}

// ---------------- fused scores + softmax + attention write + PV ----------------
// Swapped-operand QK: mfma(K,Q) -> D[row=key][col=q], so each lane owns one q-row
// (q = l16) with 4 CONSECUTIVE keys per tile. P stays packed bf16x2 in 64 VGPRs:
//  - attention written straight from registers (no LDS round-trip)
//  - PV staging LDS is wave-private (no barriers), 2 chunks of 256 keys -> 33.8 KB
//  - __launch_bounds__(256,3): 3 blocks/CU = 12 waves/CU (was 8, LDS-limited at 66 KB)
__global__ __launch_bounds__(256, 3) void attn_kernel(
    const short* __restrict__ Qp, const short* __restrict__ Kp, const short* __restrict__ Vt,
    const int* __restrict__ mask, float* __restrict__ attn, short* __restrict__ Obf)
{
    __shared__ short sc[4][16][264];   // wave-private P staging, 33792 B (aliased by osc in epilogue)
    __shared__ float wsum[4][16];
    __shared__ float vinv[16];

    const int qt = blockIdx.x, h = blockIdx.y, b = blockIdx.z;
    const int bh = b*Hn + h;
    const int tid = threadIdx.x;
    const int wave = tid >> 6, lane = tid & 63;
    const int l16 = lane & 15, quad = lane >> 4;
    const int q0 = qt * 16;

    const short* Qbase = Qp + (size_t)bh*Sn*Dn;
    const short* Kbase = Kp + (size_t)bh*Sn*Dn;
    const short* Vbase = Vt + (size_t)bh*Dn*Sn;

    // Q fragments (B operand now): lane holds q = q0+l16, d = quad*8+j
    short8v qa0 = *(const short8v*)(Qbase + (q0 + l16)*Dn + quad*8);
    short8v qa1 = *(const short8v*)(Qbase + (q0 + l16)*Dn + 32 + quad*8);

    const float SCALE = 0.0441941738241592f;   // 1/sqrt(512)
    const int kw = wave * 512;                 // this wave's key chunk
    const int km = b*Sn;

    // ---- Phase A: QK^T (swapped), exp, pack to bf16x2 registers ----
    unsigned int pk[32][2];                    // P[q=l16][kw + t*16 + quad*4 + {0..3}]
    float rs = 0.f;                            // row-sum partial for q = l16
    #pragma unroll
    for (int t = 0; t < 32; t++){
        const int k0 = kw + t*16;
        short8v kb0 = *(const short8v*)(Kbase + (k0 + l16)*Dn + quad*8);
        short8v kb1 = *(const short8v*)(Kbase + (k0 + l16)*Dn + 32 + quad*8);
        float4v a = {0.f,0.f,0.f,0.f};
        a = __builtin_amdgcn_mfma_f32_16x16x32_bf16(kb0, qa0, a, 0,0,0);
        a = __builtin_amdgcn_mfma_f32_16x16x32_bf16(kb1, qa1, a, 0,0,0);
        const int4 mk = *(const int4*)(mask + km + k0 + quad*4);   // 4 consecutive keys
        // |score| <= ~3 -> exp without max-subtraction is safe; masked -> exactly 0
        float p0 = mk.x ? __expf(a[0]*SCALE) : 0.f;
        float p1 = mk.y ? __expf(a[1]*SCALE) : 0.f;
        float p2 = mk.z ? __expf(a[2]*SCALE) : 0.f;
        float p3 = mk.w ? __expf(a[3]*SCALE) : 0.f;
        rs += (p0 + p1) + (p2 + p3);
        pk[t][0] = pack2(p0, p1);
        pk[t][1] = pack2(p2, p3);
    }

    // ---- Phase B: row-sum across quads (same q), then across waves ----
    rs += __shfl_xor(rs, 16);
    rs += __shfl_xor(rs, 32);
    if (lane < 16) wsum[wave][lane] = rs;
    __syncthreads();
    const float stot = wsum[0][l16] + wsum[1][l16] + wsum[2][l16] + wsum[3][l16];
    const float vq = (stot > 0.f) ? 1.f/stot : 0.f;    // this lane's q-row normalizer
    if (tid < 16) vinv[tid] = vq;

    // ---- Phase C: write normalized attention straight from registers ----
    float* arow = attn + (size_t)bh*Sn*Sn + (size_t)(q0 + l16)*Sn + kw + quad*4;
    #pragma unroll
    for (int t = 0; t < 32; t++){
        float4v o;
        o[0] = bf2f((short)(pk[t][0] & 0xffff)) * vq;
        o[1] = bf2f((short)(pk[t][0] >> 16))    * vq;
        o[2] = bf2f((short)(pk[t][1] & 0xffff)) * vq;
        o[3] = bf2f((short)(pk[t][1] >> 16))    * vq;
        __builtin_nontemporal_store(o, (float4v*)(arow + t*16));
    }

    // ---- Phase D: P @ V over this wave's 512 keys, 2 chunks of 256 (wave-private LDS) ----
    // swapped PV: mfma(Vt_frag, P_frag) -> D[row=d][col=q]
    float4v acc0 = {0.f,0.f,0.f,0.f}, acc1 = {0.f,0.f,0.f,0.f},
            acc2 = {0.f,0.f,0.f,0.f}, acc3 = {0.f,0.f,0.f,0.f};
    short* scw = &sc[wave][0][0];
    #pragma unroll
    for (int c = 0; c < 2; c++){
        #pragma unroll
        for (int tc = 0; tc < 16; tc++){       // stage chunk: ds_write_b64, conflict-free
            uint2v w2;
            w2[0] = pk[c*16 + tc][0];
            w2[1] = pk[c*16 + tc][1];
            *(uint2v*)(scw + l16*264 + tc*16 + quad*4) = w2;
        }
        #pragma unroll
        for (int ks = 0; ks < 8; ks++){
            const int kv = kw + c*256 + ks*32 + quad*8;
            short8v pa  = *(const short8v*)(scw + l16*264 + ks*32 + quad*8);
            short8v vb0 = *(const short8v*)(Vbase + (size_t)( 0 + l16)*Sn + kv);
            short8v vb1 = *(const short8v*)(Vbase + (size_t)(16 + l16)*Sn + kv);
            short8v vb2 = *(const short8v*)(Vbase + (size_t)(32 + l16)*Sn + kv);
            short8v vb3 = *(const short8v*)(Vbase + (size_t)(48 + l16)*Sn + kv);
            acc0 = __builtin_amdgcn_mfma_f32_16x16x32_bf16(vb0, pa, acc0, 0,0,0);
            acc1 = __builtin_amdgcn_mfma_f32_16x16x32_bf16(vb1, pa, acc1, 0,0,0);
            acc2 = __builtin_amdgcn_mfma_f32_16x16x32_bf16(vb2, pa, acc2, 0,0,0);
            acc3 = __builtin_amdgcn_mfma_f32_16x16x32_bf16(vb3, pa, acc3, 0,0,0);
        }
    }

    // ---- Phase E: cross-wave O reduction (osc aliases sc; padded rows: stride 68) ----
    __syncthreads();                       // all waves done with their sc before alias-write
    float* osc = (float*)&sc[0][0][0];     // [4][16][68] fp32 = 17408 B
    {
        float* orow = osc + (wave*16 + l16)*68 + quad*4;
        *(float4v*)(orow +  0) = acc0;     // d = 0..15  : quad*4+r
        *(float4v*)(orow + 16) = acc1;
        *(float4v*)(orow + 32) = acc2;
        *(float4v*)(orow + 48) = acc3;
    }
    __syncthreads();
    {
        const int row = tid >> 4, dbase = (tid & 15)*4;
        float4v v =  *(const float4v*)(osc + ( 0 + row)*68 + dbase);
        v = v + *(const float4v*)(osc + (16 + row)*68 + dbase);
        v = v + *(const float4v*)(osc + (32 + row)*68 + dbase);
        v = v + *(const float4v*)(osc + (48 + row)*68 + dbase);
        const float s = vinv[row];
        short4 o;
        o.x = f2bf(v[0]*s); o.y = f2bf(v[1]*s); o.z = f2bf(v[2]*s); o.w = f2bf(v[3]*s);
        *(short4*)(Obf + ((size_t)b*Sn + q0 + row)*En + h*Dn + dbase) = o;
    }
}

// ---------------- out = O @ Wo^T + bo  (8192 x 512 x 512, bf16 MFMA) ----------------
__global__ __launch_bounds__(256) void outproj_kernel(
    const short* __restrict__ Obf, const short* __restrict__ Wob,
    const float* __restrict__ bo, float* __restrict__ out)
{
    const int nt = blockIdx.x;     // 8 col tiles of 64
    const int mt = blockIdx.y;     // 128 row tiles of 64
    const int wave = threadIdx.x >> 6, lane = threadIdx.x & 63;
    const int l16 = lane & 15, quad = lane >> 4;
    const int m0 = mt*64 + wave*16;
    const int n0 = nt*64;

    float4v acc0 = {0.f,0.f,0.f,0.f}, acc1 = {0.f,0.f,0.f,0.f},
            acc2 = {0.f,0.f,0.f,0.f}, acc3 = {0.f,0.f,0.f,0.f};
    for (int ks = 0; ks < 16; ks++){
        const int kb = ks*32 + quad*8;
        short8v af = *(const short8v*)(Obf + (size_t)(m0 + l16)*En + kb);
        short8v b0 = *(const short8v*)(Wob + (size_t)(n0 +  0 + l16)*En + kb);
        short8v b1 = *(const short8v*)(Wob + (size_t)(n0 + 16 + l16)*En + kb);
        short8v b2 = *(const short8v*)(Wob + (size_t)(n0 + 32 + l16)*En + kb);
        short8v b3 = *(const short8v*)(Wob + (size_t)(n0 + 48 + l16)*En + kb);
        acc0 = __builtin_amdgcn_mfma_f32_16x16x32_bf16(af, b0, acc0, 0,0,0);
        acc1 = __builtin_amdgcn_mfma_f32_16x16x32_bf16(af, b1, acc1, 0,0,0);
        acc2 = __builtin_amdgcn_mfma_f32_16x16x32_bf16(af, b2, acc2, 0,0,0);
        acc3 = __builtin_amdgcn_mfma_f32_16x16x32_bf16(af, b3, acc3, 0,0,0);
    }
    #pragma unroll
    for (int t = 0; t < 4; t++){
        float4v a = (t==0)?acc0:((t==1)?acc1:((t==2)?acc2:acc3));
        const int e = n0 + t*16 + l16;
        const float bias = bo[e];
        #pragma unroll
        for (int r = 0; r < 4; r++)
            out[(size_t)(m0 + quad*4 + r)*En + e] = a[r] + bias;
    }
}

extern "C" void kernel_launch(void* const* d_in, const int* in_sizes, int n_in,
                              void* d_out, int out_size, void* d_ws, size_t ws_size,
                              hipStream_t stream)
{
    const float* values = (const float*)d_in[0];
    const float* keys   = (const float*)d_in[1];
    const float* query  = (const float*)d_in[2];
    const int*   mask   = (const int*)d_in[3];
    const float* Wv = (const float*)d_in[4];
    const float* Wk = (const float*)d_in[5];
    const float* Wq = (const float*)d_in[6];
    const float* Wo = (const float*)d_in[7];
    const float* bo = (const float*)d_in[8];

    float* out  = (float*)d_out;
    float* attn = out + (size_t)Bn*Sn*En;   // outputs concatenated: out, then attention

    short* Qp  = (short*)d_ws;                       // [bh][s][64] bf16
    short* Kp  = Qp + (size_t)Bn*Hn*Sn*Dn;           // [bh][k][64] bf16
    short* Vt  = Kp + (size_t)Bn*Hn*Sn*Dn;           // [bh][64][k] bf16 (transposed)
    short* Obf = Vt + (size_t)Bn*Hn*Sn*Dn;           // [b*s][512] bf16
    short* Wob = Obf + (size_t)Bn*Sn*En;             // [512][512] bf16

    wo_cvt_kernel<<<dim3((En*En)/1024), 256, 0, stream>>>(Wo, Wob);
    proj_kernel<<<dim3(Sn/64, Bn*Hn, 3), 256, 0, stream>>>(values, keys, query, Wv, Wk, Wq, Qp, Kp, Vt);
    attn_kernel<<<dim3(Sn/16, Hn, Bn), 256, 0, stream>>>(Qp, Kp, Vt, mask, attn, Obf);
    outproj_kernel<<<dim3(En/64, (Bn*Sn)/64), 256, 0, stream>>>(Obf, Wob, bo, out);
}

// Round 2
// 880.383 us; speedup vs baseline: 1.0020x; 1.0020x over previous
//
#include <hip/hip_runtime.h>
#include <hip/hip_bf16.h>

#define Bn 4
#define Sn 2048
#define Hn 8
#define Dn 64
#define En 512

typedef __attribute__((ext_vector_type(8))) short short8v;
typedef __attribute__((ext_vector_type(4))) float float4v;
typedef __attribute__((ext_vector_type(2))) unsigned int uint2v;

__device__ __forceinline__ short f2bf(float x){
    __hip_bfloat16 h = __float2bfloat16(x);
    return *reinterpret_cast<short*>(&h);
}
__device__ __forceinline__ float bf2f(short s){
    union { unsigned int u; float f; } c;
    c.u = ((unsigned int)(unsigned short)s) << 16;
    return c.f;
}
__device__ __forceinline__ unsigned int pack2(float lo, float hi){
    return (unsigned int)(unsigned short)f2bf(lo) | ((unsigned int)(unsigned short)f2bf(hi) << 16);
}

// ---------------- Wo fp32 -> bf16 ----------------
__global__ __launch_bounds__(256) void wo_cvt_kernel(const float* __restrict__ Wo,
                                                     short* __restrict__ Wob){
    int i = (blockIdx.x * 256 + threadIdx.x) * 4;
    float4 v = *(const float4*)(Wo + i);
    short4 o;
    o.x = f2bf(v.x); o.y = f2bf(v.y); o.z = f2bf(v.z); o.w = f2bf(v.w);
    *(short4*)(Wob + i) = o;
}

// ---------------- per-head input projections ----------------
// blockIdx.z: 0: values*Wv -> Vt[bh][d][k] (transposed); 1: keys*Wk -> Kp[bh][k][d]; 2: query*Wq -> Qp[bh][q][d]
__global__ __launch_bounds__(256) void proj_kernel(
    const float* __restrict__ values, const float* __restrict__ keys, const float* __restrict__ query,
    const float* __restrict__ Wv, const float* __restrict__ Wk, const float* __restrict__ Wq,
    short* __restrict__ Qp, short* __restrict__ Kp, short* __restrict__ Vt)
{
    const int sel = blockIdx.z;
    const float* X = (sel == 0) ? values : ((sel == 1) ? keys : query);
    const float* W = (sel == 0) ? Wv : ((sel == 1) ? Wk : Wq);
    const int bh = blockIdx.y;
    const int b = bh >> 3, h = bh & 7;
    const int s0 = blockIdx.x * 64;
    const int wave = threadIdx.x >> 6;
    const int lane = threadIdx.x & 63;
    const int l16 = lane & 15, quad = lane >> 4;

    // W-fragments: lane holds e = t*16+l16, d = st*32+quad*8+j (W rows are contiguous in d)
    short8v bw[4][2];
    #pragma unroll
    for (int t = 0; t < 4; t++){
      #pragma unroll
      for (int st = 0; st < 2; st++){
        const float* wp = W + (t*16 + l16)*64 + st*32 + quad*8;
        float4 w0 = *(const float4*)(wp);
        float4 w1 = *(const float4*)(wp + 4);
        short8v f;
        f[0]=f2bf(w0.x); f[1]=f2bf(w0.y); f[2]=f2bf(w0.z); f[3]=f2bf(w0.w);
        f[4]=f2bf(w1.x); f[5]=f2bf(w1.y); f[6]=f2bf(w1.z); f[7]=f2bf(w1.w);
        bw[t][st] = f;
      }
    }

    const int row = s0 + wave*16 + l16;
    short8v fa[2];
    #pragma unroll
    for (int st = 0; st < 2; st++){
        const float* xp = X + ((size_t)b*Sn + row)*En + h*Dn + st*32 + quad*8;
        float4 x0 = *(const float4*)(xp);
        float4 x1 = *(const float4*)(xp + 4);
        short8v f;
        f[0]=f2bf(x0.x); f[1]=f2bf(x0.y); f[2]=f2bf(x0.z); f[3]=f2bf(x0.w);
        f[4]=f2bf(x1.x); f[5]=f2bf(x1.y); f[6]=f2bf(x1.z); f[7]=f2bf(x1.w);
        fa[st] = f;
    }

    if (sel == 0){
        // D[row = s : quad*4+r][col = e : l16]  -> Vt[bh][e][k]: short4 along k
        const int rbase = s0 + wave*16 + quad*4;
        #pragma unroll
        for (int t = 0; t < 4; t++){
            float4v a = {0.f,0.f,0.f,0.f};
            a = __builtin_amdgcn_mfma_f32_16x16x32_bf16(fa[0], bw[t][0], a, 0,0,0);
            a = __builtin_amdgcn_mfma_f32_16x16x32_bf16(fa[1], bw[t][1], a, 0,0,0);
            int e = t*16 + l16;
            short4 pk;
            pk.x = f2bf(a[0]); pk.y = f2bf(a[1]); pk.z = f2bf(a[2]); pk.w = f2bf(a[3]);
            *(short4*)(Vt + ((size_t)bh*Dn + e)*Sn + rbase) = pk;   // 4 consecutive k
        }
    } else {
        // swapped: D[row = e : quad*4+r][col = s : l16] -> [s][d]: short4 along d
        short* dst = (sel == 1) ? Kp : Qp;
        #pragma unroll
        for (int t = 0; t < 4; t++){
            float4v a = {0.f,0.f,0.f,0.f};
            a = __builtin_amdgcn_mfma_f32_16x16x32_bf16(bw[t][0], fa[0], a, 0,0,0);
            a = __builtin_amdgcn_mfma_f32_16x16x32_bf16(bw[t][1], fa[1], a, 0,0,0);
            short4 pk;
            pk.x = f2bf(a[0]); pk.y = f2bf(a[1]); pk.z = f2bf(a[2]); pk.w = f2bf(a[3]);
            *(short4*)(dst + ((size_t)bh*Sn + row)*Dn + t*16 + quad*4) = pk;
        }
    }
}

// ---------------- fused scores + softmax + attention write + PV ----------------
// Swapped-operand QK: mfma(K,Q) -> D[row=key][col=q]; each lane owns q-row l16,
// 4 consecutive keys per tile; P packed bf16x2 in 64 VGPRs.
// R2 change: attention is written FROM THE STAGED LDS TILE, one full row
// (256 fp32 = 1 KB contiguous) per store instruction -> complete 128B lines,
// nt-safe, no write amplification. (R1 wrote 16 rows x 64B per instruction ->
// partial-line NT stores -> WRITE_SIZE 853MB vs 545MB ideal.)
__global__ __launch_bounds__(256, 3) void attn_kernel(
    const short* __restrict__ Qp, const short* __restrict__ Kp, const short* __restrict__ Vt,
    const int* __restrict__ mask, float* __restrict__ attn, short* __restrict__ Obf)
{
    __shared__ short sc[4][16][264];   // wave-private P staging, 33792 B (aliased by osc in epilogue)
    __shared__ float wsum[4][16];
    __shared__ float vinv[16];

    const int qt = blockIdx.x, h = blockIdx.y, b = blockIdx.z;
    const int bh = b*Hn + h;
    const int tid = threadIdx.x;
    const int wave = tid >> 6, lane = tid & 63;
    const int l16 = lane & 15, quad = lane >> 4;
    const int q0 = qt * 16;

    const short* Qbase = Qp + (size_t)bh*Sn*Dn;
    const short* Kbase = Kp + (size_t)bh*Sn*Dn;
    const short* Vbase = Vt + (size_t)bh*Dn*Sn;

    // Q fragments (B operand): lane holds q = q0+l16, d = quad*8+j
    short8v qa0 = *(const short8v*)(Qbase + (q0 + l16)*Dn + quad*8);
    short8v qa1 = *(const short8v*)(Qbase + (q0 + l16)*Dn + 32 + quad*8);

    const float SCALE = 0.0441941738241592f;   // 1/sqrt(512)
    const int kw = wave * 512;                 // this wave's key chunk
    const int km = b*Sn;

    // ---- Phase A: QK^T (swapped), exp, pack to bf16x2 registers ----
    unsigned int pk[32][2];                    // P[q=l16][kw + t*16 + quad*4 + {0..3}]
    float rs = 0.f;                            // row-sum partial for q = l16
    #pragma unroll
    for (int t = 0; t < 32; t++){
        const int k0 = kw + t*16;
        short8v kb0 = *(const short8v*)(Kbase + (k0 + l16)*Dn + quad*8);
        short8v kb1 = *(const short8v*)(Kbase + (k0 + l16)*Dn + 32 + quad*8);
        float4v a = {0.f,0.f,0.f,0.f};
        a = __builtin_amdgcn_mfma_f32_16x16x32_bf16(kb0, qa0, a, 0,0,0);
        a = __builtin_amdgcn_mfma_f32_16x16x32_bf16(kb1, qa1, a, 0,0,0);
        const int4 mk = *(const int4*)(mask + km + k0 + quad*4);   // 4 consecutive keys
        // |score| <= ~3 -> exp without max-subtraction is safe; masked -> exactly 0
        float p0 = mk.x ? __expf(a[0]*SCALE) : 0.f;
        float p1 = mk.y ? __expf(a[1]*SCALE) : 0.f;
        float p2 = mk.z ? __expf(a[2]*SCALE) : 0.f;
        float p3 = mk.w ? __expf(a[3]*SCALE) : 0.f;
        rs += (p0 + p1) + (p2 + p3);
        pk[t][0] = pack2(p0, p1);
        pk[t][1] = pack2(p2, p3);
    }

    // ---- Phase B: row-sum across quads, then across waves; publish vinv[16] ----
    rs += __shfl_xor(rs, 16);
    rs += __shfl_xor(rs, 32);
    if (lane < 16) wsum[wave][lane] = rs;
    __syncthreads();
    if (tid < 16){
        float s = wsum[0][tid] + wsum[1][tid] + wsum[2][tid] + wsum[3][tid];
        vinv[tid] = (s > 0.f) ? 1.f/s : 0.f;
    }
    __syncthreads();

    // ---- Phase C+D: stage chunk -> PV MFMAs -> coalesced attention row-writes ----
    // swapped PV: mfma(Vt_frag, P_frag) -> D[row=d][col=q]
    float4v acc0 = {0.f,0.f,0.f,0.f}, acc1 = {0.f,0.f,0.f,0.f},
            acc2 = {0.f,0.f,0.f,0.f}, acc3 = {0.f,0.f,0.f,0.f};
    short* scw = &sc[wave][0][0];
    float* abase = attn + (size_t)bh*Sn*Sn;
    #pragma unroll
    for (int c = 0; c < 2; c++){
        #pragma unroll
        for (int tc = 0; tc < 16; tc++){       // stage chunk: ds_write_b64, conflict-free
            uint2v w2;
            w2[0] = pk[c*16 + tc][0];
            w2[1] = pk[c*16 + tc][1];
            *(uint2v*)(scw + l16*264 + tc*16 + quad*4) = w2;
        }
        #pragma unroll
        for (int ks = 0; ks < 8; ks++){
            const int kv = kw + c*256 + ks*32 + quad*8;
            short8v pa  = *(const short8v*)(scw + l16*264 + ks*32 + quad*8);
            short8v vb0 = *(const short8v*)(Vbase + (size_t)( 0 + l16)*Sn + kv);
            short8v vb1 = *(const short8v*)(Vbase + (size_t)(16 + l16)*Sn + kv);
            short8v vb2 = *(const short8v*)(Vbase + (size_t)(32 + l16)*Sn + kv);
            short8v vb3 = *(const short8v*)(Vbase + (size_t)(48 + l16)*Sn + kv);
            acc0 = __builtin_amdgcn_mfma_f32_16x16x32_bf16(vb0, pa, acc0, 0,0,0);
            acc1 = __builtin_amdgcn_mfma_f32_16x16x32_bf16(vb1, pa, acc1, 0,0,0);
            acc2 = __builtin_amdgcn_mfma_f32_16x16x32_bf16(vb2, pa, acc2, 0,0,0);
            acc3 = __builtin_amdgcn_mfma_f32_16x16x32_bf16(vb3, pa, acc3, 0,0,0);
        }
        // attention rows for this chunk: 64 lanes x float4 = 1 KB contiguous per row
        #pragma unroll
        for (int row = 0; row < 16; row++){
            short4 s4 = *(const short4*)(scw + row*264 + lane*4);   // ds_read_b64, 2-way (free)
            const float vr = vinv[row];
            float4v o;
            o[0] = bf2f(s4.x)*vr; o[1] = bf2f(s4.y)*vr;
            o[2] = bf2f(s4.z)*vr; o[3] = bf2f(s4.w)*vr;
            __builtin_nontemporal_store(o,
                (float4v*)(abase + (size_t)(q0 + row)*Sn + kw + c*256 + lane*4));
        }
    }

    // ---- Phase E: cross-wave O reduction (osc aliases sc; padded rows: stride 68) ----
    __syncthreads();                       // all waves done with their sc before alias-write
    float* osc = (float*)&sc[0][0][0];     // [4][16][68] fp32 = 17408 B
    {
        float* orow = osc + (wave*16 + l16)*68 + quad*4;
        *(float4v*)(orow +  0) = acc0;     // d = 0..15  : quad*4+r
        *(float4v*)(orow + 16) = acc1;
        *(float4v*)(orow + 32) = acc2;
        *(float4v*)(orow + 48) = acc3;
    }
    __syncthreads();
    {
        const int row = tid >> 4, dbase = (tid & 15)*4;
        float4v v =  *(const float4v*)(osc + ( 0 + row)*68 + dbase);
        v = v + *(const float4v*)(osc + (16 + row)*68 + dbase);
        v = v + *(const float4v*)(osc + (32 + row)*68 + dbase);
        v = v + *(const float4v*)(osc + (48 + row)*68 + dbase);
        const float s = vinv[row];
        short4 o;
        o.x = f2bf(v[0]*s); o.y = f2bf(v[1]*s); o.z = f2bf(v[2]*s); o.w = f2bf(v[3]*s);
        *(short4*)(Obf + ((size_t)b*Sn + q0 + row)*En + h*Dn + dbase) = o;
    }
}

// ---------------- out = O @ Wo^T + bo  (8192 x 512 x 512, bf16 MFMA) ----------------
__global__ __launch_bounds__(256) void outproj_kernel(
    const short* __restrict__ Obf, const short* __restrict__ Wob,
    const float* __restrict__ bo, float* __restrict__ out)
{
    const int nt = blockIdx.x;     // 8 col tiles of 64
    const int mt = blockIdx.y;     // 128 row tiles of 64
    const int wave = threadIdx.x >> 6, lane = threadIdx.x & 63;
    const int l16 = lane & 15, quad = lane >> 4;
    const int m0 = mt*64 + wave*16;
    const int n0 = nt*64;

    float4v acc0 = {0.f,0.f,0.f,0.f}, acc1 = {0.f,0.f,0.f,0.f},
            acc2 = {0.f,0.f,0.f,0.f}, acc3 = {0.f,0.f,0.f,0.f};
    for (int ks = 0; ks < 16; ks++){
        const int kb = ks*32 + quad*8;
        short8v af = *(const short8v*)(Obf + (size_t)(m0 + l16)*En + kb);
        short8v b0 = *(const short8v*)(Wob + (size_t)(n0 +  0 + l16)*En + kb);
        short8v b1 = *(const short8v*)(Wob + (size_t)(n0 + 16 + l16)*En + kb);
        short8v b2 = *(const short8v*)(Wob + (size_t)(n0 + 32 + l16)*En + kb);
        short8v b3 = *(const short8v*)(Wob + (size_t)(n0 + 48 + l16)*En + kb);
        acc0 = __builtin_amdgcn_mfma_f32_16x16x32_bf16(af, b0, acc0, 0,0,0);
        acc1 = __builtin_amdgcn_mfma_f32_16x16x32_bf16(af, b1, acc1, 0,0,0);
        acc2 = __builtin_amdgcn_mfma_f32_16x16x32_bf16(af, b2, acc2, 0,0,0);
        acc3 = __builtin_amdgcn_mfma_f32_16x16x32_bf16(af, b3, acc3, 0,0,0);
    }
    #pragma unroll
    for (int t = 0; t < 4; t++){
        float4v a = (t==0)?acc0:((t==1)?acc1:((t==2)?acc2:acc3));
        const int e = n0 + t*16 + l16;
        const float bias = bo[e];
        #pragma unroll
        for (int r = 0; r < 4; r++)
            out[(size_t)(m0 + quad*4 + r)*En + e] = a[r] + bias;
    }
}

extern "C" void kernel_launch(void* const* d_in, const int* in_sizes, int n_in,
                              void* d_out, int out_size, void* d_ws, size_t ws_size,
                              hipStream_t stream)
{
    const float* values = (const float*)d_in[0];
    const float* keys   = (const float*)d_in[1];
    const float* query  = (const float*)d_in[2];
    const int*   mask   = (const int*)d_in[3];
    const float* Wv = (const float*)d_in[4];
    const float* Wk = (const float*)d_in[5];
    const float* Wq = (const float*)d_in[6];
    const float* Wo = (const float*)d_in[7];
    const float* bo = (const float*)d_in[8];

    float* out  = (float*)d_out;
    float* attn = out + (size_t)Bn*Sn*En;   // outputs concatenated: out, then attention

    short* Qp  = (short*)d_ws;                       // [bh][s][64] bf16
    short* Kp  = Qp + (size_t)Bn*Hn*Sn*Dn;           // [bh][k][64] bf16
    short* Vt  = Kp + (size_t)Bn*Hn*Sn*Dn;           // [bh][64][k] bf16 (transposed)
    short* Obf = Vt + (size_t)Bn*Hn*Sn*Dn;           // [b*s][512] bf16
    short* Wob = Obf + (size_t)Bn*Sn*En;             // [512][512] bf16

    wo_cvt_kernel<<<dim3((En*En)/1024), 256, 0, stream>>>(Wo, Wob);
    proj_kernel<<<dim3(Sn/64, Bn*Hn, 3), 256, 0, stream>>>(values, keys, query, Wv, Wk, Wq, Qp, Kp, Vt);
    attn_kernel<<<dim3(Sn/16, Hn, Bn), 256, 0, stream>>>(Qp, Kp, Vt, mask, attn, Obf);
    outproj_kernel<<<dim3(En/64, (Bn*Sn)/64), 256, 0, stream>>>(Obf, Wob, bo, out);
}